// Round 4
// baseline (763.686 us; speedup 1.0000x reference)
//
#include <hip/hip_runtime.h>
#include <stdint.h>

typedef unsigned short ushort_t;
typedef __attribute__((ext_vector_type(8))) short bf16x8;
typedef __attribute__((ext_vector_type(4))) float f32x4;

#define BB 2
#define SS 2048
#define DD 1024
#define HH 16
#define HDD 64
#define MEMM 512
#define KTOT 2560   // MEMM + SS
#define NKB 80      // KTOT/32 k-blocks per 16-row panel
#define NROWS (BB*HH*SS)   // 65536 score rows

// Packed score layout: panel p = global_row/16, k-block kb = k/32.
// Block (p,kb) = 1 KB at sbuf[(p*NKB+kb)*512], lane l holds row p*16+(l&15),
// k = kb*32+(l>>4)*8 .. +8 (exactly the mfma_16x16x32 A-fragment pv consumes).
// Packed V^T layout: block (bh,kb) = 4 KB at vt[((bh*NKB+kb)*4+nt)*512],
// lane l holds d-row nt*16+(l&15), same k slicing.

// ---------- helpers ----------
__device__ __forceinline__ float bf2f(uint32_t u) {
    return __uint_as_float(u << 16);
}
__device__ __forceinline__ ushort_t f2bf(float f) {
    uint32_t u = __float_as_uint(f);
    uint32_t r = (u + 0x7FFFu + ((u >> 16) & 1u)) >> 16;
    return (ushort_t)r;
}
__device__ __forceinline__ uint32_t mapkey(uint32_t u) {
    return (u & 0x8000u) ? (0xFFFFu ^ u) : (u | 0x8000u);
}
__device__ __forceinline__ uint32_t unmapkey(uint32_t k) {
    return (k & 0x8000u) ? (k ^ 0x8000u) : (0xFFFFu ^ k);
}

// ---------- cast hidden f32 -> bf16 ----------
__global__ __launch_bounds__(256) void cast_hidden_kernel(
    const float* __restrict__ h, ushort_t* __restrict__ hb)
{
    size_t i0 = ((size_t)blockIdx.x * 256 + threadIdx.x) * 16;  // 4M elems / 16
    ushort_t o[16];
#pragma unroll
    for (int j = 0; j < 4; ++j) {
        float4 v = *(const float4*)&h[i0 + j * 4];
        o[j * 4 + 0] = f2bf(v.x); o[j * 4 + 1] = f2bf(v.y);
        o[j * 4 + 2] = f2bf(v.z); o[j * 4 + 3] = f2bf(v.w);
    }
    *(uint4*)&hb[i0] = *(uint4*)&o[0];
    *(uint4*)&hb[i0 + 8] = *(uint4*)&o[8];
}

// ---------- transpose+cast weights: W[k][n] f32 -> Wt[n][k] bf16 ----------
__global__ __launch_bounds__(256) void transw_kernel(
    const float* __restrict__ Wq, const float* __restrict__ Wk,
    const float* __restrict__ Wv, const float* __restrict__ Wo,
    ushort_t* __restrict__ WtAll)
{
    __shared__ ushort_t T[64][66];
    const int z = blockIdx.z;
    const float* W = (z == 0) ? Wq : (z == 1) ? Wk : (z == 2) ? Wv : Wo;
    ushort_t* dst = WtAll + (size_t)z * DD * DD;
    const int k0 = blockIdx.x * 64, n0 = blockIdx.y * 64;
    const int t = threadIdx.x;
    const int kk = t >> 2, c4 = (t & 3) * 16;
#pragma unroll
    for (int j = 0; j < 4; ++j) {
        float4 v = *(const float4*)&W[(size_t)(k0 + kk) * DD + n0 + c4 + j * 4];
        T[kk][c4 + j * 4 + 0] = f2bf(v.x);
        T[kk][c4 + j * 4 + 1] = f2bf(v.y);
        T[kk][c4 + j * 4 + 2] = f2bf(v.z);
        T[kk][c4 + j * 4 + 3] = f2bf(v.w);
    }
    __syncthreads();
    const int nn = t >> 2, kc = (t & 3) * 16;
    ushort_t tmp[16];
#pragma unroll
    for (int j = 0; j < 16; ++j) tmp[j] = T[kc + j][nn];
    *(uint4*)&dst[(size_t)(n0 + nn) * DD + k0 + kc] = *(uint4*)&tmp[0];
    *(uint4*)&dst[(size_t)(n0 + nn) * DD + k0 + kc + 8] = *(uint4*)&tmp[8];
}

// ---------- 128x128-tile bf16 MFMA GEMM (m93-style LDS staging) ----------
__global__ __launch_bounds__(256) void gemm128_kernel(
    const ushort_t* __restrict__ A, const ushort_t* __restrict__ Bt, int mode,
    const float* __restrict__ bq, const float* __restrict__ bk, const float* __restrict__ bv,
    float* __restrict__ outf,
    ushort_t* __restrict__ q_bf, ushort_t* __restrict__ kbf, ushort_t* __restrict__ vbf,
    float* __restrict__ nk, float* __restrict__ nv)
{
    __shared__ __align__(16) ushort_t As[128 * 32];
    __shared__ __align__(16) ushort_t Bs[128 * 32];
    const int tid = threadIdx.x;
    const int lane = tid & 63, w = tid >> 6;
    const int wm = w >> 1, wn = w & 1;
    const int row16 = lane & 15, quad = lane >> 4;
    const int n0 = blockIdx.x * 128, m0 = blockIdx.y * 128;

    const int r0 = tid >> 2, c0 = (tid & 3) * 8;
    const int r1 = (tid + 256) >> 2, c1 = ((tid + 256) & 3) * 8;

    f32x4 acc[4][4];
#pragma unroll
    for (int i = 0; i < 4; ++i)
#pragma unroll
        for (int j = 0; j < 4; ++j) acc[i][j] = (f32x4){0.f, 0.f, 0.f, 0.f};

    for (int k0 = 0; k0 < DD; k0 += 32) {
        *(uint4*)&As[tid * 8]         = *(const uint4*)&A [(size_t)(m0 + r0) * DD + k0 + c0];
        *(uint4*)&As[(tid + 256) * 8] = *(const uint4*)&A [(size_t)(m0 + r1) * DD + k0 + c1];
        *(uint4*)&Bs[tid * 8]         = *(const uint4*)&Bt[(size_t)(n0 + r0) * DD + k0 + c0];
        *(uint4*)&Bs[(tid + 256) * 8] = *(const uint4*)&Bt[(size_t)(n0 + r1) * DD + k0 + c1];
        __syncthreads();
        bf16x8 af[4], bfr[4];
#pragma unroll
        for (int mt = 0; mt < 4; ++mt)
            af[mt] = *(const bf16x8*)&As[(wm * 64 + mt * 16 + row16) * 32 + quad * 8];
#pragma unroll
        for (int nt = 0; nt < 4; ++nt)
            bfr[nt] = *(const bf16x8*)&Bs[(wn * 64 + nt * 16 + row16) * 32 + quad * 8];
#pragma unroll
        for (int mt = 0; mt < 4; ++mt)
#pragma unroll
            for (int nt = 0; nt < 4; ++nt)
                acc[mt][nt] = __builtin_amdgcn_mfma_f32_16x16x32_bf16(
                    af[mt], bfr[nt], acc[mt][nt], 0, 0, 0);
        __syncthreads();
    }

#pragma unroll
    for (int nt = 0; nt < 4; ++nt) {
        const int nb = n0 + wn * 64 + nt * 16;       // tile-uniform
        if (mode == 0) {
#pragma unroll
            for (int mt = 0; mt < 4; ++mt) {
#pragma unroll
                for (int r = 0; r < 4; ++r) {
                    int m = m0 + wm * 64 + mt * 16 + quad * 4 + r;
                    int n = nb + row16;
                    outf[(size_t)m * DD + n] = acc[mt][nt][r] + bq[n];
                }
            }
        } else {
            const int sel = nb >> 10;
            const float* bias = (sel == 0) ? bq : (sel == 1) ? bk : bv;
#pragma unroll
            for (int mt = 0; mt < 4; ++mt) {
#pragma unroll
                for (int r = 0; r < 4; ++r) {
                    int m = m0 + wm * 64 + mt * 16 + quad * 4 + r;
                    int nn = (nb + row16) & 1023;
                    float v = acc[mt][nt][r] + bias[nn];
                    int b = m >> 11, s = m & (SS - 1);
                    int h = nn >> 6, d = nn & 63;
                    size_t bh = (size_t)b * HH + h;
                    if (sel == 0) {
                        q_bf[(bh * SS + s) * HDD + d] = f2bf(v);
                    } else {
                        ushort_t* dst = (sel == 1) ? kbf : vbf;
                        dst[(bh * KTOT + MEMM + s) * HDD + d] = f2bf(v);
                        if (s >= SS - MEMM) {
                            float* nf = (sel == 1) ? nk : nv;
                            nf[(bh * MEMM + (s - (SS - MEMM))) * HDD + d] = v;
                        }
                    }
                }
            }
        }
    }
}

// ---------- cast past_k/past_v f32 -> bf16 cache heads ----------
__global__ __launch_bounds__(256) void cast_past_kernel(
    const float* __restrict__ pk, const float* __restrict__ pv,
    ushort_t* __restrict__ kbf, ushort_t* __restrict__ vbf)
{
    int idx = blockIdx.x * 256 + threadIdx.x;  // BB*HH*MEMM*HDD = 1048576
    int bh = idx >> 15;
    int rem = idx & 32767;
    size_t dst = (size_t)bh * KTOT * HDD + rem;
    kbf[dst] = f2bf(pk[idx]);
    vbf[dst] = f2bf(pv[idx]);
}

// ---------- transpose V -> packed fragment layout ----------
__global__ __launch_bounds__(256) void transpose_v_kernel(
    const ushort_t* __restrict__ vbf, ushort_t* __restrict__ vt)
{
    __shared__ ushort_t T[64][72];
    const int k0 = blockIdx.x * 64;
    const int bh = blockIdx.y;
    const int t = threadIdx.x;
    const int rr = t >> 3, cc = (t & 7) * 8;
#pragma unroll
    for (int p = 0; p < 2; ++p) {
        int kk = p * 32 + rr;
        *(uint4*)&T[kk][cc] =
            *(const uint4*)(vbf + ((size_t)bh * KTOT + k0 + kk) * HDD + cc);
    }
    __syncthreads();
    const int ld = t & 63, nt = t >> 6;
    const int sr = ld & 15, q = ld >> 4;
#pragma unroll
    for (int kbl = 0; kbl < 2; ++kbl) {
        ushort_t tmp[8];
#pragma unroll
        for (int j = 0; j < 8; ++j) tmp[j] = T[kbl * 32 + q * 8 + j][nt * 16 + sr];
        *(uint4*)(vt + (((size_t)bh * NKB + (k0 >> 5) + kbl) * 4 + nt) * 512 + ld * 8)
            = *(uint4*)tmp;
    }
}

// ---------- scores: MFMA (K prefetch), wave-private LDS transpose, ----------
// ---------- packed 1-KB-contiguous k-block stores, no barriers ----------
__global__ __launch_bounds__(256) void score_kernel(
    const ushort_t* __restrict__ qbf, const ushort_t* __restrict__ kbf,
    ushort_t* __restrict__ sbuf, int bh0)
{
    __shared__ __align__(16) ushort_t Ts[64][264];
    const int w = threadIdx.x >> 6, lane = threadIdx.x & 63;
    const int kt = blockIdx.x, qt = blockIdx.y;
    const int lbh = blockIdx.z, bh = bh0 + lbh;
    const int m0 = qt * 64 + w * 16;
    const int row16 = lane & 15, quad = lane >> 4;

    const ushort_t* qrow = qbf + ((size_t)bh * SS + m0 + row16) * HDD + quad * 8;
    bf16x8 a0 = *(const bf16x8*)qrow;
    bf16x8 a1 = *(const bf16x8*)(qrow + 32);
    const ushort_t* kbase = kbf + ((size_t)bh * KTOT + kt * 256 + row16) * HDD + quad * 8;

    bf16x8 b0c = *(const bf16x8*)kbase;
    bf16x8 b1c = *(const bf16x8*)(kbase + 32);
#pragma unroll
    for (int nt = 0; nt < 16; ++nt) {
        bf16x8 b0n, b1n;
        if (nt < 15) {
            const ushort_t* kr = kbase + (size_t)(nt + 1) * 16 * HDD;
            b0n = *(const bf16x8*)kr;
            b1n = *(const bf16x8*)(kr + 32);
        }
        f32x4 acc = {0.f, 0.f, 0.f, 0.f};
        acc = __builtin_amdgcn_mfma_f32_16x16x32_bf16(a0, b0c, acc, 0, 0, 0);
        acc = __builtin_amdgcn_mfma_f32_16x16x32_bf16(a1, b1c, acc, 0, 0, 0);
#pragma unroll
        for (int r = 0; r < 4; ++r)
            Ts[w * 16 + quad * 4 + r][nt * 16 + row16] = f2bf(acc[r] * 0.125f);
        b0c = b0n; b1c = b1n;
    }
    // wave-private readback (wave w only touches rows w*16..w*16+15 it wrote).
    // Packed store: 8 k-blocks, each 1 KB fully contiguous.
    const int pnl = lbh * (SS / 16) + qt * 4 + w;
    ushort_t* dstb = sbuf + ((size_t)pnl * NKB + kt * 8) * 512 + lane * 8;
    const int c0 = (lane >> 4) * 8;
    const int rs = w * 16 + (lane & 15);
#pragma unroll
    for (int kbl = 0; kbl < 8; ++kbl)
        *(uint4*)(dstb + kbl * 512) = *(const uint4*)&Ts[rs][kbl * 32 + c0];
}

// ---------- wave helpers ----------
__device__ __forceinline__ uint32_t wave_iscan(uint32_t x, int lane) {
#pragma unroll
    for (int d = 1; d < 64; d <<= 1) {
        uint32_t t = __shfl_up(x, d, 64);
        if (lane >= d) x += t;
    }
    return x;
}
__device__ __forceinline__ void select_from_counts(
    const uint32_t* c, uint32_t R, int lane, uint32_t* bin_out, uint32_t* rem_out)
{
    uint32_t s = c[0] + c[1] + c[2] + c[3];
    uint32_t incl = wave_iscan(s, lane);
    uint32_t excl = incl - s;
    uint64_t bal = __ballot(incl > R);
    int fl = __ffsll((unsigned long long)bal) - 1;
    uint32_t exf = __shfl(excl, fl, 64);
    uint32_t c0 = __shfl(c[0], fl, 64), c1 = __shfl(c[1], fl, 64);
    uint32_t c2 = __shfl(c[2], fl, 64), c3 = __shfl(c[3], fl, 64);
    uint32_t cc[4] = {c0, c1, c2, c3};
    uint32_t cum = exf, bin = fl * 4, rem = 0;
#pragma unroll
    for (int i = 0; i < 4; ++i) {
        if (cum + cc[i] > R) { bin = fl * 4 + i; rem = R - cum; break; }
        cum += cc[i];
    }
    *bin_out = bin;
    *rem_out = rem;
}

// ---------- per-panel quantile: block = 16 rows, fully-contiguous reads ----------
// Packed layout binds lane l to row (l&15): per-row class counts are a
// 2-shuffle reduce; per-row low-byte histograms in LDS (row-padded 257 ->
// distinct banks). Exact block-cooperative fallback for out-of-range rows.
__global__ __launch_bounds__(256) void quant_kernel(
    const ushort_t* __restrict__ sbuf, float* __restrict__ thr_out, int bh0)
{
    __shared__ uint32_t cw[4][16][2];
    __shared__ uint32_t histA[16][257];
    __shared__ uint32_t histB[16][257];
    const int tid = threadIdx.x;
    const int w = tid >> 6, lane = tid & 63;
    const int sr = lane & 15;
    const int p = blockIdx.x;
    const size_t grow0 = (size_t)bh0 * SS + (size_t)p * 16;

    // each wave streams 20 contiguous 1-KB k-blocks
    const ushort_t* src = sbuf + ((size_t)p * NKB + w * 20) * 512 + lane * 8;
    uint4 W[20];
#pragma unroll
    for (int c = 0; c < 20; ++c) W[c] = *(const uint4*)(src + c * 512);

    // pass 1: per-lane class counts over 160 keys
    uint32_t nBel = 0, nA = 0, nB = 0, nC = 0;
#pragma unroll
    for (int c = 0; c < 20; ++c) {
        uint32_t ww[4] = {W[c].x, W[c].y, W[c].z, W[c].w};
#pragma unroll
        for (int q = 0; q < 4; ++q) {
            uint32_t t0 = (ww[q] >> 8) & 255u, t1 = ww[q] >> 24;
            nBel += (t0 >= 0xC1u); nBel += (t1 >= 0xC1u);
            nA   += (t0 == 0xC0u); nA   += (t1 == 0xC0u);
            nB   += (t0 == 0xBFu); nB   += (t1 == 0xBFu);
            nC   += (t0 == 0xBEu); nC   += (t1 == 0xBEu);
        }
    }
    uint32_t p0 = nBel | (nA << 16), p1 = nB | (nC << 16);
    p0 += (uint32_t)__shfl_xor(p0, 16, 64); p0 += (uint32_t)__shfl_xor(p0, 32, 64);
    p1 += (uint32_t)__shfl_xor(p1, 16, 64); p1 += (uint32_t)__shfl_xor(p1, 32, 64);
    if (lane < 16) { cw[w][lane][0] = p0; cw[w][lane][1] = p1; }
    __syncthreads();
    const uint32_t P0 = cw[0][sr][0] + cw[1][sr][0] + cw[2][sr][0] + cw[3][sr][0];
    const uint32_t P1 = cw[0][sr][1] + cw[1][sr][1] + cw[2][sr][1] + cw[3][sr][1];
    const uint32_t C0 = P0 & 0xFFFFu;
    const uint32_t C1 = C0 + (P0 >> 16);
    const uint32_t C2 = C1 + (P1 & 0xFFFFu);
    const uint32_t C3 = C2 + (P1 >> 16);

    uint32_t tbA = 0x1FFu, remA = 0, tbB = 0x1FFu, remB = 0;
    bool okA = true, okB = true;
    if (255u < C0)      okA = false;
    else if (255u < C1) { tbA = 0xC0u; remA = 255u - C0; }
    else if (255u < C2) { tbA = 0xBFu; remA = 255u - C1; }
    else if (255u < C3) { tbA = 0xBEu; remA = 255u - C2; }
    else okA = false;
    if (256u < C0)      okB = false;
    else if (256u < C1) { tbB = 0xC0u; remB = 256u - C0; }
    else if (256u < C2) { tbB = 0xBFu; remB = 256u - C1; }
    else if (256u < C3) { tbB = 0xBEu; remB = 256u - C2; }
    else okB = false;
    const uint32_t okRu = (okA && okB) ? 1u : 0u;
    if (!okRu) { tbA = 0x1FFu; tbB = 0x1FFu; }   // suppress fast-path atomics

    // clear hists
    for (int i = tid; i < 16 * 257; i += 256) {
        ((uint32_t*)histA)[i] = 0u;
        ((uint32_t*)histB)[i] = 0u;
    }
    __syncthreads();

    const uint32_t tbBn = (tbB != tbA) ? tbB : 0x1FFu;
#pragma unroll
    for (int c = 0; c < 20; ++c) {
        uint32_t ww[4] = {W[c].x, W[c].y, W[c].z, W[c].w};
#pragma unroll
        for (int q = 0; q < 4; ++q) {
            uint32_t t0 = (ww[q] >> 8) & 255u, lo0 = ww[q] & 255u;
            uint32_t t1 = ww[q] >> 24,         lo1 = (ww[q] >> 16) & 255u;
            if (t0 == tbA)  atomicAdd(&histA[sr][lo0 ^ 255u], 1u);
            if (t1 == tbA)  atomicAdd(&histA[sr][lo1 ^ 255u], 1u);
            if (t0 == tbBn) atomicAdd(&histB[sr][lo0 ^ 255u], 1u);
            if (t1 == tbBn) atomicAdd(&histB[sr][lo1 ^ 255u], 1u);
        }
    }
    __syncthreads();

    // selection: wave w handles rows w*4 .. w*4+3
    for (int j = 0; j < 4; ++j) {
        const int rho = w * 4 + j;
        const uint32_t okr = (uint32_t)__shfl((int)okRu, rho, 64);
        if (!okr) continue;     // wave-uniform (row-scalar)
        const uint32_t tbAr  = (uint32_t)__shfl((int)tbA, rho, 64);
        const uint32_t tbBr  = (uint32_t)__shfl((int)tbB, rho, 64);
        const uint32_t remAr = (uint32_t)__shfl((int)remA, rho, 64);
        const uint32_t remBr = (uint32_t)__shfl((int)remB, rho, 64);
        uint32_t c4[4];
#pragma unroll
        for (int i = 0; i < 4; ++i) c4[i] = histA[rho][lane * 4 + i];
        uint32_t idxA, rr, idxB;
        select_from_counts(c4, remAr, lane, &idxA, &rr);
        uint32_t rawA = (tbAr << 8) | (idxA ^ 255u);
        uint32_t rawB;
        if (tbBr == tbAr) {
            select_from_counts(c4, remBr, lane, &idxB, &rr);
            rawB = (tbAr << 8) | (idxB ^ 255u);
        } else {
            uint32_t d4[4];
#pragma unroll
            for (int i = 0; i < 4; ++i) d4[i] = histB[rho][lane * 4 + i];
            select_from_counts(d4, remBr, lane, &idxB, &rr);
            rawB = (tbBr << 8) | (idxB ^ 255u);
        }
        if (lane == 0) {
            float fA = bf2f(rawA), fB = bf2f(rawB);
            thr_out[grow0 + rho] = fA + 0.9f * (fB - fA);
        }
    }

    // exact fallback for rows whose rank fell outside the candidate bins.
    // fail mask is block-uniform (computed from row-uniform C's).
    uint32_t fail = (uint32_t)__ballot(lane < 16 && !okRu) & 0xFFFFu;
    __syncthreads();
    while (fail) {
        const int rho = __ffs(fail) - 1; fail &= fail - 1;
        uint32_t rawAB[2];
        for (int t = 0; t < 2; ++t) {
            const uint32_t R = 255u + (uint32_t)t;
            for (int i = tid; i < 257; i += 256) histA[0][i] = 0u;
            __syncthreads();
            if (sr == rho) {
#pragma unroll
                for (int c = 0; c < 20; ++c) {
                    uint32_t ww[4] = {W[c].x, W[c].y, W[c].z, W[c].w};
#pragma unroll
                    for (int q = 0; q < 4; ++q) {
                        atomicAdd(&histA[0][mapkey(ww[q] & 0xFFFFu) >> 8], 1u);
                        atomicAdd(&histA[0][mapkey(ww[q] >> 16) >> 8], 1u);
                    }
                }
            }
            __syncthreads();
            uint32_t c4[4];
#pragma unroll
            for (int i = 0; i < 4; ++i) c4[i] = histA[0][lane * 4 + i];
            uint32_t binM, rem;
            select_from_counts(c4, R, lane, &binM, &rem);
            __syncthreads();
            for (int i = tid; i < 257; i += 256) histA[0][i] = 0u;
            __syncthreads();
            if (sr == rho) {
#pragma unroll
                for (int c = 0; c < 20; ++c) {
                    uint32_t ww[4] = {W[c].x, W[c].y, W[c].z, W[c].w};
#pragma unroll
                    for (int q = 0; q < 4; ++q) {
                        uint32_t m0k = mapkey(ww[q] & 0xFFFFu);
                        uint32_t m1k = mapkey(ww[q] >> 16);
                        if ((m0k >> 8) == binM) atomicAdd(&histA[0][m0k & 255u], 1u);
                        if ((m1k >> 8) == binM) atomicAdd(&histA[0][m1k & 255u], 1u);
                    }
                }
            }
            __syncthreads();
#pragma unroll
            for (int i = 0; i < 4; ++i) c4[i] = histA[0][lane * 4 + i];
            uint32_t low, r2;
            select_from_counts(c4, rem, lane, &low, &r2);
            rawAB[t] = unmapkey((binM << 8) | low);
            __syncthreads();
        }
        if (tid == 0) {
            float fA = bf2f(rawAB[0]), fB = bf2f(rawAB[1]);
            thr_out[grow0 + rho] = fA + 0.9f * (fB - fA);
        }
    }
}

// ---------- softmax + PV, packed streaming reads, in-block K-split ----------
__global__ __launch_bounds__(1024) void pv_kernel(
    const ushort_t* __restrict__ sbuf, const ushort_t* __restrict__ vt,
    const float* __restrict__ thr_arr,
    const int* __restrict__ amask, ushort_t* __restrict__ attn_bf, int bh0)
{
    __shared__ float red[8][64][21];   // 43 KB; 21-word stride: conflict-free
    const int tid = threadIdx.x;
    const int lane = tid & 63, w = tid >> 6;
    const int wr = w & 3, wq = w >> 2;
    const int row16 = lane & 15, quad = lane >> 4;
    const int qt = blockIdx.x;
    const int lbh = blockIdx.y, bh = bh0 + lbh;
    const int b = bh >> 4, h = bh & 15;
    const int m0 = qt * 64 + wr * 16;      // this wave's first row
    const int kb0 = wq * (NKB / 4);        // k-block quarter [kb0, kb0+20)
    const int kbe = kb0 + NKB / 4;

    const int pnl = lbh * (SS / 16) + qt * 4 + wr;
    const ushort_t* abase = sbuf + (size_t)pnl * NKB * 512 + lane * 8;
    const ushort_t* bbase = vt + (size_t)bh * NKB * 2048 + lane * 8;
    const float thr = thr_arr[(size_t)bh * SS + m0 + row16];
    const int* amq = amask + b * SS + quad * 8;

    // ones B-fragment: B[k][c] = 1 iff c==0 -> output col 0 = row sums
    const uint32_t ow = (row16 == 0) ? 0x3F803F80u : 0u;
    uint4 ov; ov.x = ow; ov.y = ow; ov.z = ow; ov.w = ow;
    bf16x8 onesf; *(uint4*)&onesf = ov;

    f32x4 acc[4];
#pragma unroll
    for (int i = 0; i < 4; ++i) acc[i] = (f32x4){0.f, 0.f, 0.f, 0.f};
    f32x4 acc5 = (f32x4){0.f, 0.f, 0.f, 0.f};

    uint4 a_nxt = *(const uint4*)(abase + (size_t)kb0 * 512);
    uint4 b_nxt[4];
#pragma unroll
    for (int nt = 0; nt < 4; ++nt)
        b_nxt[nt] = *(const uint4*)(bbase + (size_t)kb0 * 2048 + nt * 512);
    int4 m_nxt0 = {1, 1, 1, 1}, m_nxt1 = {1, 1, 1, 1};
    if (kb0 * 32 >= MEMM) {
        m_nxt0 = *(const int4*)(amq + kb0 * 32 - MEMM);
        m_nxt1 = *(const int4*)(amq + kb0 * 32 - MEMM + 4);
    }

    for (int kb = kb0; kb < kbe; ++kb) {
        uint4 a_cur = a_nxt;
        uint4 b_cur[4] = {b_nxt[0], b_nxt[1], b_nxt[2], b_nxt[3]};
        int4 mc0 = m_nxt0, mc1 = m_nxt1;
        const int kbn = kb + 1;
        if (kbn < kbe) {
            a_nxt = *(const uint4*)(abase + (size_t)kbn * 512);
#pragma unroll
            for (int nt = 0; nt < 4; ++nt)
                b_nxt[nt] = *(const uint4*)(bbase + (size_t)kbn * 2048 + nt * 512);
            const int kn = kbn * 32;
            if (kn >= MEMM) {
                m_nxt0 = *(const int4*)(amq + kn - MEMM);
                m_nxt1 = *(const int4*)(amq + kn - MEMM + 4);
            }
        }
        uint32_t u[8] = {a_cur.x & 0xFFFFu, a_cur.x >> 16, a_cur.y & 0xFFFFu, a_cur.y >> 16,
                         a_cur.z & 0xFFFFu, a_cur.z >> 16, a_cur.w & 0xFFFFu, a_cur.w >> 16};
        int mm[8] = {mc0.x, mc0.y, mc0.z, mc0.w, mc1.x, mc1.y, mc1.z, mc1.w};
        const bool masked = (kb * 32 >= MEMM);
        float wv[8];
#pragma unroll
        for (int j = 0; j < 8; ++j) {
            float s = bf2f(u[j]);
            bool keep = (s >= thr);
            if (masked) keep = keep && (mm[j] != 0);
            wv[j] = keep ? __expf(s) : 0.f;
        }
        uint4 aq;
        asm("v_cvt_pk_bf16_f32 %0, %1, %2" : "=v"(aq.x) : "v"(wv[0]), "v"(wv[1]));
        asm("v_cvt_pk_bf16_f32 %0, %1, %2" : "=v"(aq.y) : "v"(wv[2]), "v"(wv[3]));
        asm("v_cvt_pk_bf16_f32 %0, %1, %2" : "=v"(aq.z) : "v"(wv[4]), "v"(wv[5]));
        asm("v_cvt_pk_bf16_f32 %0, %1, %2" : "=v"(aq.w) : "v"(wv[6]), "v"(wv[7]));
        bf16x8 af;
        *(uint4*)&af = aq;
#pragma unroll
        for (int nt = 0; nt < 4; ++nt) {
            bf16x8 bf;
            *(uint4*)&bf = b_cur[nt];
            acc[nt] = __builtin_amdgcn_mfma_f32_16x16x32_bf16(af, bf, acc[nt], 0, 0, 0);
        }
        acc5 = __builtin_amdgcn_mfma_f32_16x16x32_bf16(af, onesf, acc5, 0, 0, 0);
    }

    // ---- combine across K quarters (halving rounds) ----
    if (w >= 8) {
        float* dst = &red[w - 8][lane][0];
#pragma unroll
        for (int nt = 0; nt < 4; ++nt)
#pragma unroll
            for (int r = 0; r < 4; ++r) dst[nt * 4 + r] = acc[nt][r];
#pragma unroll
        for (int r = 0; r < 4; ++r) dst[16 + r] = acc5[r];
    }
    __syncthreads();
    if (w < 8) {
        const float* s = &red[w][lane][0];
#pragma unroll
        for (int nt = 0; nt < 4; ++nt)
#pragma unroll
            for (int r = 0; r < 4; ++r) acc[nt][r] += s[nt * 4 + r];
#pragma unroll
        for (int r = 0; r < 4; ++r) acc5[r] += s[16 + r];
    }
    __syncthreads();
    if (w >= 4 && w < 8) {
        float* dst = &red[w - 4][lane][0];
#pragma unroll
        for (int nt = 0; nt < 4; ++nt)
#pragma unroll
            for (int r = 0; r < 4; ++r) dst[nt * 4 + r] = acc[nt][r];
#pragma unroll
        for (int r = 0; r < 4; ++r) dst[16 + r] = acc5[r];
    }
    __syncthreads();
    if (w < 4) {
        const float* s = &red[w][lane][0];
#pragma unroll
        for (int nt = 0; nt < 4; ++nt)
#pragma unroll
            for (int r = 0; r < 4; ++r) acc[nt][r] += s[nt * 4 + r];
#pragma unroll
        for (int r = 0; r < 4; ++r) acc5[r] += s[16 + r];

        float rinv[4];
#pragma unroll
        for (int r = 0; r < 4; ++r) {
            float rs = __shfl(acc5[r], quad * 16, 64);
            rinv[r] = 1.0f / rs;
        }
#pragma unroll
        for (int nt = 0; nt < 4; ++nt) {
#pragma unroll
            for (int r = 0; r < 4; ++r) {
                int row = quad * 4 + r;
                float val = acc[nt][r] * rinv[r];
                attn_bf[((size_t)b * SS + m0 + row) * DD + h * HDD + nt * 16 + row16] = f2bf(val);
            }
        }
    }
}

extern "C" void kernel_launch(void* const* d_in, const int* in_sizes, int n_in,
                              void* d_out, int out_size, void* d_ws, size_t ws_size,
                              hipStream_t stream)
{
    const float* hidden = (const float*)d_in[0];
    const int*   amask  = (const int*)d_in[1];
    const float* past_k = (const float*)d_in[2];
    const float* past_v = (const float*)d_in[3];
    const float* Wq = (const float*)d_in[4];
    const float* bq = (const float*)d_in[5];
    const float* Wk = (const float*)d_in[6];
    const float* bk = (const float*)d_in[7];
    const float* Wv = (const float*)d_in[8];
    const float* bv = (const float*)d_in[9];
    const float* Wo = (const float*)d_in[10];
    const float* bo = (const float*)d_in[11];

    float* out    = (float*)d_out;
    float* nk_out = out + (size_t)BB * SS * DD;
    float* nv_out = nk_out + (size_t)BB * HH * MEMM * HDD;

    char* base = (char*)d_ws;
    size_t off = 0;
    auto alloc = [&](size_t bytes) {
        char* p = base + off;
        off += (bytes + 255) & ~(size_t)255;
        return p;
    };
    ushort_t* hb    = (ushort_t*)alloc((size_t)BB * SS * DD * 2);            // 8 MB
    ushort_t* WtAll = (ushort_t*)alloc((size_t)4 * DD * DD * 2);             // 8 MB
    ushort_t* q_bf  = (ushort_t*)alloc((size_t)BB * HH * SS * HDD * 2);      // 8 MB
    ushort_t* kbf   = (ushort_t*)alloc((size_t)BB * HH * KTOT * HDD * 2);    // 10 MB
    ushort_t* vbf   = (ushort_t*)alloc((size_t)BB * HH * KTOT * HDD * 2);    // 10 MB
    ushort_t* vt    = (ushort_t*)alloc((size_t)BB * HH * NKB * 4 * 512 * 2); // 10.5 MB packed
    ushort_t* abf   = (ushort_t*)alloc((size_t)BB * SS * DD * 2);            // 8 MB
    float* thr_arr  = (float*)alloc((size_t)NROWS * 4);
    size_t fixed = off;
    const size_t sbuf_full = (size_t)NROWS * KTOT * 2;                       // 335.5 MB packed
    int nchunks = 32;
    for (int c = 1; c <= 32; c <<= 1) {
        if (fixed + sbuf_full / c + 256 <= ws_size) { nchunks = c; break; }
    }
    ushort_t* sbuf = (ushort_t*)alloc(sbuf_full / nchunks);
    const int bhpc = (BB * HH) / nchunks;

    dim3 blk(256);

    cast_hidden_kernel<<<dim3(1024), blk, 0, stream>>>(hidden, hb);
    transw_kernel<<<dim3(16, 16, 4), blk, 0, stream>>>(Wq, Wk, Wv, Wo, WtAll);
    // fused QKV: one GEMM, N=3072 (Wq|Wk|Wv transposes adjacent in WtAll)
    gemm128_kernel<<<dim3(24, 32), blk, 0, stream>>>(
        hb, WtAll, 1, bq, bk, bv, nullptr, q_bf, kbf, vbf, nk_out, nv_out);
    cast_past_kernel<<<dim3(4096), blk, 0, stream>>>(past_k, past_v, kbf, vbf);
    transpose_v_kernel<<<dim3(KTOT / 64, BB * HH), blk, 0, stream>>>(vbf, vt);

    for (int ci = 0; ci < nchunks; ++ci) {
        int bh0 = ci * bhpc;
        score_kernel<<<dim3(KTOT / 256, SS / 64, bhpc), blk, 0, stream>>>(q_bf, kbf, sbuf, bh0);
        quant_kernel<<<dim3(bhpc * (SS / 16)), blk, 0, stream>>>(sbuf, thr_arr, bh0);
        pv_kernel<<<dim3(SS / 64, bhpc), dim3(1024), 0, stream>>>(sbuf, vt, thr_arr,
                                                                  amask, abf, bh0);
    }
    // O-projection
    gemm128_kernel<<<dim3(8, 32), blk, 0, stream>>>(
        abf, WtAll + (size_t)3 * DD * DD, 0, bo, nullptr, nullptr, out,
        nullptr, nullptr, nullptr, nullptr, nullptr);
}

// Round 5
// 567.819 us; speedup vs baseline: 1.3449x; 1.3449x over previous
//
#include <hip/hip_runtime.h>
#include <stdint.h>

typedef unsigned short ushort_t;
typedef __attribute__((ext_vector_type(8))) short bf16x8;
typedef __attribute__((ext_vector_type(4))) float f32x4;

#define BB 2
#define SS 2048
#define DD 1024
#define HH 16
#define HDD 64
#define MEMM 512
#define KTOT 2560   // MEMM + SS
#define NKB 80      // KTOT/32 k-blocks per 16-row panel
#define NROWS (BB*HH*SS)   // 65536 score rows

// Packed score layout: panel p = global_row/16, k-block kb = k/32.
// Block (p,kb) = 1 KB at sbuf[(p*NKB+kb)*512], lane l holds row p*16+(l&15),
// k = kb*32+(l>>4)*8 .. +8 (exactly the mfma_16x16x32 A-fragment pv consumes).
// Packed V^T layout: block (bh,kb) = 4 KB at vt[((bh*NKB+kb)*4+nt)*512],
// lane l holds d-row nt*16+(l&15), same k slicing.

// ---------- helpers ----------
__device__ __forceinline__ float bf2f(uint32_t u) {
    return __uint_as_float(u << 16);
}
__device__ __forceinline__ ushort_t f2bf(float f) {
    uint32_t u = __float_as_uint(f);
    uint32_t r = (u + 0x7FFFu + ((u >> 16) & 1u)) >> 16;
    return (ushort_t)r;
}
__device__ __forceinline__ uint32_t mapkey(uint32_t u) {
    return (u & 0x8000u) ? (0xFFFFu ^ u) : (u | 0x8000u);
}
__device__ __forceinline__ uint32_t unmapkey(uint32_t k) {
    return (k & 0x8000u) ? (k ^ 0x8000u) : (0xFFFFu ^ k);
}

// ---------- cast hidden f32 -> bf16 ----------
__global__ __launch_bounds__(256) void cast_hidden_kernel(
    const float* __restrict__ h, ushort_t* __restrict__ hb)
{
    size_t i0 = ((size_t)blockIdx.x * 256 + threadIdx.x) * 16;  // 4M elems / 16
    ushort_t o[16];
#pragma unroll
    for (int j = 0; j < 4; ++j) {
        float4 v = *(const float4*)&h[i0 + j * 4];
        o[j * 4 + 0] = f2bf(v.x); o[j * 4 + 1] = f2bf(v.y);
        o[j * 4 + 2] = f2bf(v.z); o[j * 4 + 3] = f2bf(v.w);
    }
    *(uint4*)&hb[i0] = *(uint4*)&o[0];
    *(uint4*)&hb[i0 + 8] = *(uint4*)&o[8];
}

// ---------- transpose+cast weights: W[k][n] f32 -> Wt[n][k] bf16 ----------
__global__ __launch_bounds__(256) void transw_kernel(
    const float* __restrict__ Wq, const float* __restrict__ Wk,
    const float* __restrict__ Wv, const float* __restrict__ Wo,
    ushort_t* __restrict__ WtAll)
{
    __shared__ ushort_t T[64][66];
    const int z = blockIdx.z;
    const float* W = (z == 0) ? Wq : (z == 1) ? Wk : (z == 2) ? Wv : Wo;
    ushort_t* dst = WtAll + (size_t)z * DD * DD;
    const int k0 = blockIdx.x * 64, n0 = blockIdx.y * 64;
    const int t = threadIdx.x;
    const int kk = t >> 2, c4 = (t & 3) * 16;
#pragma unroll
    for (int j = 0; j < 4; ++j) {
        float4 v = *(const float4*)&W[(size_t)(k0 + kk) * DD + n0 + c4 + j * 4];
        T[kk][c4 + j * 4 + 0] = f2bf(v.x);
        T[kk][c4 + j * 4 + 1] = f2bf(v.y);
        T[kk][c4 + j * 4 + 2] = f2bf(v.z);
        T[kk][c4 + j * 4 + 3] = f2bf(v.w);
    }
    __syncthreads();
    const int nn = t >> 2, kc = (t & 3) * 16;
    ushort_t tmp[16];
#pragma unroll
    for (int j = 0; j < 16; ++j) tmp[j] = T[kc + j][nn];
    *(uint4*)&dst[(size_t)(n0 + nn) * DD + k0 + kc] = *(uint4*)&tmp[0];
    *(uint4*)&dst[(size_t)(n0 + nn) * DD + k0 + kc + 8] = *(uint4*)&tmp[8];
}

// ---------- 128x128-tile bf16 MFMA GEMM (m93-style LDS staging) ----------
__global__ __launch_bounds__(256) void gemm128_kernel(
    const ushort_t* __restrict__ A, const ushort_t* __restrict__ Bt, int mode,
    const float* __restrict__ bq, const float* __restrict__ bk, const float* __restrict__ bv,
    float* __restrict__ outf,
    ushort_t* __restrict__ q_bf, ushort_t* __restrict__ kbf, ushort_t* __restrict__ vbf,
    float* __restrict__ nk, float* __restrict__ nv)
{
    __shared__ __align__(16) ushort_t As[128 * 32];
    __shared__ __align__(16) ushort_t Bs[128 * 32];
    const int tid = threadIdx.x;
    const int lane = tid & 63, w = tid >> 6;
    const int wm = w >> 1, wn = w & 1;
    const int row16 = lane & 15, quad = lane >> 4;
    const int n0 = blockIdx.x * 128, m0 = blockIdx.y * 128;

    const int r0 = tid >> 2, c0 = (tid & 3) * 8;
    const int r1 = (tid + 256) >> 2, c1 = ((tid + 256) & 3) * 8;

    f32x4 acc[4][4];
#pragma unroll
    for (int i = 0; i < 4; ++i)
#pragma unroll
        for (int j = 0; j < 4; ++j) acc[i][j] = (f32x4){0.f, 0.f, 0.f, 0.f};

    for (int k0 = 0; k0 < DD; k0 += 32) {
        *(uint4*)&As[tid * 8]         = *(const uint4*)&A [(size_t)(m0 + r0) * DD + k0 + c0];
        *(uint4*)&As[(tid + 256) * 8] = *(const uint4*)&A [(size_t)(m0 + r1) * DD + k0 + c1];
        *(uint4*)&Bs[tid * 8]         = *(const uint4*)&Bt[(size_t)(n0 + r0) * DD + k0 + c0];
        *(uint4*)&Bs[(tid + 256) * 8] = *(const uint4*)&Bt[(size_t)(n0 + r1) * DD + k0 + c1];
        __syncthreads();
        bf16x8 af[4], bfr[4];
#pragma unroll
        for (int mt = 0; mt < 4; ++mt)
            af[mt] = *(const bf16x8*)&As[(wm * 64 + mt * 16 + row16) * 32 + quad * 8];
#pragma unroll
        for (int nt = 0; nt < 4; ++nt)
            bfr[nt] = *(const bf16x8*)&Bs[(wn * 64 + nt * 16 + row16) * 32 + quad * 8];
#pragma unroll
        for (int mt = 0; mt < 4; ++mt)
#pragma unroll
            for (int nt = 0; nt < 4; ++nt)
                acc[mt][nt] = __builtin_amdgcn_mfma_f32_16x16x32_bf16(
                    af[mt], bfr[nt], acc[mt][nt], 0, 0, 0);
        __syncthreads();
    }

#pragma unroll
    for (int nt = 0; nt < 4; ++nt) {
        const int nb = n0 + wn * 64 + nt * 16;       // tile-uniform
        if (mode == 0) {
#pragma unroll
            for (int mt = 0; mt < 4; ++mt) {
#pragma unroll
                for (int r = 0; r < 4; ++r) {
                    int m = m0 + wm * 64 + mt * 16 + quad * 4 + r;
                    int n = nb + row16;
                    outf[(size_t)m * DD + n] = acc[mt][nt][r] + bq[n];
                }
            }
        } else {
            const int sel = nb >> 10;
            const float* bias = (sel == 0) ? bq : (sel == 1) ? bk : bv;
#pragma unroll
            for (int mt = 0; mt < 4; ++mt) {
#pragma unroll
                for (int r = 0; r < 4; ++r) {
                    int m = m0 + wm * 64 + mt * 16 + quad * 4 + r;
                    int nn = (nb + row16) & 1023;
                    float v = acc[mt][nt][r] + bias[nn];
                    int b = m >> 11, s = m & (SS - 1);
                    int h = nn >> 6, d = nn & 63;
                    size_t bh = (size_t)b * HH + h;
                    if (sel == 0) {
                        q_bf[(bh * SS + s) * HDD + d] = f2bf(v);
                    } else {
                        ushort_t* dst = (sel == 1) ? kbf : vbf;
                        dst[(bh * KTOT + MEMM + s) * HDD + d] = f2bf(v);
                        if (s >= SS - MEMM) {
                            float* nf = (sel == 1) ? nk : nv;
                            nf[(bh * MEMM + (s - (SS - MEMM))) * HDD + d] = v;
                        }
                    }
                }
            }
        }
    }
}

// ---------- cast past_k/past_v f32 -> bf16 cache heads ----------
__global__ __launch_bounds__(256) void cast_past_kernel(
    const float* __restrict__ pk, const float* __restrict__ pv,
    ushort_t* __restrict__ kbf, ushort_t* __restrict__ vbf)
{
    int idx = blockIdx.x * 256 + threadIdx.x;  // BB*HH*MEMM*HDD = 1048576
    int bh = idx >> 15;
    int rem = idx & 32767;
    size_t dst = (size_t)bh * KTOT * HDD + rem;
    kbf[dst] = f2bf(pk[idx]);
    vbf[dst] = f2bf(pv[idx]);
}

// ---------- transpose V -> packed fragment layout ----------
__global__ __launch_bounds__(256) void transpose_v_kernel(
    const ushort_t* __restrict__ vbf, ushort_t* __restrict__ vt)
{
    __shared__ ushort_t T[64][72];
    const int k0 = blockIdx.x * 64;
    const int bh = blockIdx.y;
    const int t = threadIdx.x;
    const int rr = t >> 3, cc = (t & 7) * 8;
#pragma unroll
    for (int p = 0; p < 2; ++p) {
        int kk = p * 32 + rr;
        *(uint4*)&T[kk][cc] =
            *(const uint4*)(vbf + ((size_t)bh * KTOT + k0 + kk) * HDD + cc);
    }
    __syncthreads();
    const int ld = t & 63, nt = t >> 6;
    const int sr = ld & 15, q = ld >> 4;
#pragma unroll
    for (int kbl = 0; kbl < 2; ++kbl) {
        ushort_t tmp[8];
#pragma unroll
        for (int j = 0; j < 8; ++j) tmp[j] = T[kbl * 32 + q * 8 + j][nt * 16 + sr];
        *(uint4*)(vt + (((size_t)bh * NKB + (k0 >> 5) + kbl) * 4 + nt) * 512 + ld * 8)
            = *(uint4*)tmp;
    }
}

// ---------- scores: MFMA (K prefetch), wave-private LDS transpose, ----------
// ---------- packed 1-KB-contiguous k-block stores, no barriers ----------
__global__ __launch_bounds__(256) void score_kernel(
    const ushort_t* __restrict__ qbf, const ushort_t* __restrict__ kbf,
    ushort_t* __restrict__ sbuf, int bh0)
{
    __shared__ __align__(16) ushort_t Ts[64][264];
    const int w = threadIdx.x >> 6, lane = threadIdx.x & 63;
    const int kt = blockIdx.x, qt = blockIdx.y;
    const int lbh = blockIdx.z, bh = bh0 + lbh;
    const int m0 = qt * 64 + w * 16;
    const int row16 = lane & 15, quad = lane >> 4;

    const ushort_t* qrow = qbf + ((size_t)bh * SS + m0 + row16) * HDD + quad * 8;
    bf16x8 a0 = *(const bf16x8*)qrow;
    bf16x8 a1 = *(const bf16x8*)(qrow + 32);
    const ushort_t* kbase = kbf + ((size_t)bh * KTOT + kt * 256 + row16) * HDD + quad * 8;

    bf16x8 b0c = *(const bf16x8*)kbase;
    bf16x8 b1c = *(const bf16x8*)(kbase + 32);
#pragma unroll
    for (int nt = 0; nt < 16; ++nt) {
        bf16x8 b0n, b1n;
        if (nt < 15) {
            const ushort_t* kr = kbase + (size_t)(nt + 1) * 16 * HDD;
            b0n = *(const bf16x8*)kr;
            b1n = *(const bf16x8*)(kr + 32);
        }
        f32x4 acc = {0.f, 0.f, 0.f, 0.f};
        acc = __builtin_amdgcn_mfma_f32_16x16x32_bf16(a0, b0c, acc, 0, 0, 0);
        acc = __builtin_amdgcn_mfma_f32_16x16x32_bf16(a1, b1c, acc, 0, 0, 0);
#pragma unroll
        for (int r = 0; r < 4; ++r)
            Ts[w * 16 + quad * 4 + r][nt * 16 + row16] = f2bf(acc[r] * 0.125f);
        b0c = b0n; b1c = b1n;
    }
    // wave-private readback (wave w only touches rows w*16..w*16+15 it wrote).
    // Packed store: 8 k-blocks, each 1 KB fully contiguous.
    const int pnl = lbh * (SS / 16) + qt * 4 + w;
    ushort_t* dstb = sbuf + ((size_t)pnl * NKB + kt * 8) * 512 + lane * 8;
    const int c0 = (lane >> 4) * 8;
    const int rs = w * 16 + (lane & 15);
#pragma unroll
    for (int kbl = 0; kbl < 8; ++kbl)
        *(uint4*)(dstb + kbl * 512) = *(const uint4*)&Ts[rs][kbl * 32 + c0];
}

// ---------- wave helpers ----------
__device__ __forceinline__ uint32_t wave_iscan(uint32_t x, int lane) {
#pragma unroll
    for (int d = 1; d < 64; d <<= 1) {
        uint32_t t = __shfl_up(x, d, 64);
        if (lane >= d) x += t;
    }
    return x;
}
__device__ __forceinline__ void select_from_counts(
    const uint32_t* c, uint32_t R, int lane, uint32_t* bin_out, uint32_t* rem_out)
{
    uint32_t s = c[0] + c[1] + c[2] + c[3];
    uint32_t incl = wave_iscan(s, lane);
    uint32_t excl = incl - s;
    uint64_t bal = __ballot(incl > R);
    int fl = __ffsll((unsigned long long)bal) - 1;
    uint32_t exf = __shfl(excl, fl, 64);
    uint32_t c0 = __shfl(c[0], fl, 64), c1 = __shfl(c[1], fl, 64);
    uint32_t c2 = __shfl(c[2], fl, 64), c3 = __shfl(c[3], fl, 64);
    uint32_t cc[4] = {c0, c1, c2, c3};
    uint32_t cum = exf, bin = fl * 4, rem = 0;
#pragma unroll
    for (int i = 0; i < 4; ++i) {
        if (cum + cc[i] > R) { bin = fl * 4 + i; rem = R - cum; break; }
        cum += cc[i];
    }
    *bin_out = bin;
    *rem_out = rem;
}

// rank-T select over a 768-ordinal u16-packed histogram (384 words).
// Returns smallest ordinal o with cumcount(<=o) > T. Wave-cooperative.
__device__ __forceinline__ uint32_t select768(
    const uint32_t* Hr, uint32_t T, int lane)
{
    uint32_t wd[6];
    uint32_t s = 0;
#pragma unroll
    for (int i = 0; i < 6; ++i) {
        wd[i] = Hr[lane * 6 + i];
        s += (wd[i] & 0xFFFFu) + (wd[i] >> 16);
    }
    uint32_t incl = wave_iscan(s, lane);
    uint32_t excl = incl - s;
    uint64_t bal = __ballot(incl > T);
    int fl = __ffsll((unsigned long long)bal) - 1;
    uint32_t cum = __shfl(excl, fl, 64);
    uint32_t wf[6];
#pragma unroll
    for (int i = 0; i < 6; ++i) wf[i] = __shfl(wd[i], fl, 64);
    uint32_t o = (uint32_t)fl * 12u;
#pragma unroll
    for (int i = 0; i < 12; ++i) {
        uint32_t cnt = (wf[i >> 1] >> ((i & 1) * 16)) & 0xFFFFu;
        if (cum + cnt > T) { o = (uint32_t)fl * 12u + (uint32_t)i; break; }
        cum += cnt;
    }
    return o;
}

// ---------- per-panel quantile: single streaming pass, no retained data ----------
// One block = 16-row panel. Each wave streams 20 contiguous 1-KB k-blocks,
// counts classes AND histograms all keys with top byte in {0xC0,0xBF,0xBE}
// into a per-row 768-ordinal u16-packed LDS histogram (value-monotone ordinal
// o = (0xC0-t)*256 + (lo^255)). Ranks 255/256 then come from one prefix scan.
// Exact fallback (rank outside window) re-reads the row from global - rare.
__global__ __launch_bounds__(256, 4) void quant_kernel(
    const ushort_t* __restrict__ sbuf, float* __restrict__ thr_out, int bh0)
{
    __shared__ uint32_t H[16][385];   // 24.6 KB; 385-stride spreads rows over banks
    __shared__ uint32_t cw[4][16];
    const int tid = threadIdx.x;
    const int w = tid >> 6, lane = tid & 63;
    const int sr = lane & 15;
    const int p = blockIdx.x;
    const size_t grow0 = (size_t)bh0 * SS + (size_t)p * 16;
    uint32_t* Hf = &H[0][0];

    for (int i = tid; i < 16 * 385; i += 256) Hf[i] = 0u;
    __syncthreads();

    // single streaming pass
    const ushort_t* src = sbuf + ((size_t)p * NKB + w * 20) * 512 + lane * 8;
    uint32_t nBel = 0, nReg = 0;
    for (int c = 0; c < 20; ++c) {
        uint4 v = *(const uint4*)(src + (size_t)c * 512);
        uint32_t ww[4] = {v.x, v.y, v.z, v.w};
#pragma unroll
        for (int q = 0; q < 4; ++q) {
            uint32_t t0 = (ww[q] >> 8) & 255u, lo0 = ww[q] & 255u;
            uint32_t t1 = ww[q] >> 24,         lo1 = (ww[q] >> 16) & 255u;
            nBel += (t0 >= 0xC1u);
            nBel += (t1 >= 0xC1u);
            uint32_t cls0 = 0xC0u - t0;
            uint32_t cls1 = 0xC0u - t1;
            if (cls0 <= 2u) {
                ++nReg;
                uint32_t o = cls0 * 256u + (lo0 ^ 255u);
                atomicAdd(&H[sr][o >> 1], 1u << ((o & 1u) << 4));
            }
            if (cls1 <= 2u) {
                ++nReg;
                uint32_t o = cls1 * 256u + (lo1 ^ 255u);
                atomicAdd(&H[sr][o >> 1], 1u << ((o & 1u) << 4));
            }
        }
    }
    uint32_t pk = nBel | (nReg << 16);
    pk += (uint32_t)__shfl_xor(pk, 16, 64);
    pk += (uint32_t)__shfl_xor(pk, 32, 64);
    if (lane < 16) cw[w][lane] = pk;
    __syncthreads();

    // selection: wave w handles rows w*4 .. w*4+3
    for (int j = 0; j < 4; ++j) {
        const int rho = w * 4 + j;
        const uint32_t P = cw[0][rho] + cw[1][rho] + cw[2][rho] + cw[3][rho];
        const uint32_t C0 = P & 0xFFFFu;
        const uint32_t C3 = C0 + (P >> 16);
        if (!(C0 <= 255u && C3 > 256u)) continue;   // row-uniform
        uint32_t o0 = select768(&H[rho][0], 255u - C0, lane);
        uint32_t o1 = select768(&H[rho][0], 256u - C0, lane);
        uint32_t rawA = ((0xC0u - (o0 >> 8)) << 8) | ((o0 & 255u) ^ 255u);
        uint32_t rawB = ((0xC0u - (o1 >> 8)) << 8) | ((o1 & 255u) ^ 255u);
        if (lane == 0) {
            float fA = bf2f(rawA), fB = bf2f(rawB);
            thr_out[grow0 + rho] = fA + 0.9f * (fB - fA);
        }
    }

    // exact fallback for rows whose rank fell outside the candidate window.
    // fail mask is block-uniform (derived from shared per-row counts).
    bool okl = false;
    if (lane < 16) {
        uint32_t P = cw[0][lane] + cw[1][lane] + cw[2][lane] + cw[3][lane];
        uint32_t C0 = P & 0xFFFFu, C3 = C0 + (P >> 16);
        okl = (C0 <= 255u) && (C3 > 256u);
    }
    uint32_t fail = (uint32_t)__ballot(lane < 16 && !okl) & 0xFFFFu;
    while (fail) {
        const int rho = __ffs(fail) - 1; fail &= fail - 1;
        uint4 Wf[5];
        if (w == 0) {
#pragma unroll
            for (int j5 = 0; j5 < 5; ++j5) {
                int s = lane + j5 * 64;
                int kb = s >> 2, q = s & 3;
                Wf[j5] = *(const uint4*)(sbuf + ((size_t)p * NKB + kb) * 512
                                         + (q * 16 + rho) * 8);
            }
        }
        uint32_t rawAB[2] = {0u, 0u};
        for (int t = 0; t < 2; ++t) {
            if (tid < 256) Hf[tid] = 0u;
            __syncthreads();
            if (w == 0) {
#pragma unroll
                for (int j5 = 0; j5 < 5; ++j5) {
                    uint32_t wwf[4] = {Wf[j5].x, Wf[j5].y, Wf[j5].z, Wf[j5].w};
#pragma unroll
                    for (int q = 0; q < 4; ++q) {
                        atomicAdd(&Hf[mapkey(wwf[q] & 0xFFFFu) >> 8], 1u);
                        atomicAdd(&Hf[mapkey(wwf[q] >> 16) >> 8], 1u);
                    }
                }
            }
            __syncthreads();
            uint32_t binM = 0, rem = 0;
            if (w == 0) {
                uint32_t c4[4];
#pragma unroll
                for (int i = 0; i < 4; ++i) c4[i] = Hf[lane * 4 + i];
                select_from_counts(c4, 255u + (uint32_t)t, lane, &binM, &rem);
            }
            __syncthreads();
            if (tid < 256) Hf[tid] = 0u;
            __syncthreads();
            if (w == 0) {
#pragma unroll
                for (int j5 = 0; j5 < 5; ++j5) {
                    uint32_t wwf[4] = {Wf[j5].x, Wf[j5].y, Wf[j5].z, Wf[j5].w};
#pragma unroll
                    for (int q = 0; q < 4; ++q) {
                        uint32_t m0k = mapkey(wwf[q] & 0xFFFFu);
                        uint32_t m1k = mapkey(wwf[q] >> 16);
                        if ((m0k >> 8) == binM) atomicAdd(&Hf[m0k & 255u], 1u);
                        if ((m1k >> 8) == binM) atomicAdd(&Hf[m1k & 255u], 1u);
                    }
                }
            }
            __syncthreads();
            if (w == 0) {
                uint32_t c4[4];
#pragma unroll
                for (int i = 0; i < 4; ++i) c4[i] = Hf[lane * 4 + i];
                uint32_t low, r2;
                select_from_counts(c4, rem, lane, &low, &r2);
                rawAB[t] = unmapkey((binM << 8) | low);
            }
            __syncthreads();
        }
        if (tid == 0) {
            float fA = bf2f(rawAB[0]), fB = bf2f(rawAB[1]);
            thr_out[grow0 + rho] = fA + 0.9f * (fB - fA);
        }
        __syncthreads();
    }
}

// ---------- softmax + PV, packed streaming reads, in-block K-split ----------
__global__ __launch_bounds__(1024) void pv_kernel(
    const ushort_t* __restrict__ sbuf, const ushort_t* __restrict__ vt,
    const float* __restrict__ thr_arr,
    const int* __restrict__ amask, ushort_t* __restrict__ attn_bf, int bh0)
{
    __shared__ float red[8][64][21];   // 43 KB; 21-word stride: conflict-free
    const int tid = threadIdx.x;
    const int lane = tid & 63, w = tid >> 6;
    const int wr = w & 3, wq = w >> 2;
    const int row16 = lane & 15, quad = lane >> 4;
    const int qt = blockIdx.x;
    const int lbh = blockIdx.y, bh = bh0 + lbh;
    const int b = bh >> 4, h = bh & 15;
    const int m0 = qt * 64 + wr * 16;      // this wave's first row
    const int kb0 = wq * (NKB / 4);        // k-block quarter [kb0, kb0+20)
    const int kbe = kb0 + NKB / 4;

    const int pnl = lbh * (SS / 16) + qt * 4 + wr;
    const ushort_t* abase = sbuf + (size_t)pnl * NKB * 512 + lane * 8;
    const ushort_t* bbase = vt + (size_t)bh * NKB * 2048 + lane * 8;
    const float thr = thr_arr[(size_t)bh * SS + m0 + row16];
    const int* amq = amask + b * SS + quad * 8;

    // ones B-fragment: B[k][c] = 1 iff c==0 -> output col 0 = row sums
    const uint32_t ow = (row16 == 0) ? 0x3F803F80u : 0u;
    uint4 ov; ov.x = ow; ov.y = ow; ov.z = ow; ov.w = ow;
    bf16x8 onesf; *(uint4*)&onesf = ov;

    f32x4 acc[4];
#pragma unroll
    for (int i = 0; i < 4; ++i) acc[i] = (f32x4){0.f, 0.f, 0.f, 0.f};
    f32x4 acc5 = (f32x4){0.f, 0.f, 0.f, 0.f};

    uint4 a_nxt = *(const uint4*)(abase + (size_t)kb0 * 512);
    uint4 b_nxt[4];
#pragma unroll
    for (int nt = 0; nt < 4; ++nt)
        b_nxt[nt] = *(const uint4*)(bbase + (size_t)kb0 * 2048 + nt * 512);
    int4 m_nxt0 = {1, 1, 1, 1}, m_nxt1 = {1, 1, 1, 1};
    if (kb0 * 32 >= MEMM) {
        m_nxt0 = *(const int4*)(amq + kb0 * 32 - MEMM);
        m_nxt1 = *(const int4*)(amq + kb0 * 32 - MEMM + 4);
    }

    for (int kb = kb0; kb < kbe; ++kb) {
        uint4 a_cur = a_nxt;
        uint4 b_cur[4] = {b_nxt[0], b_nxt[1], b_nxt[2], b_nxt[3]};
        int4 mc0 = m_nxt0, mc1 = m_nxt1;
        const int kbn = kb + 1;
        if (kbn < kbe) {
            a_nxt = *(const uint4*)(abase + (size_t)kbn * 512);
#pragma unroll
            for (int nt = 0; nt < 4; ++nt)
                b_nxt[nt] = *(const uint4*)(bbase + (size_t)kbn * 2048 + nt * 512);
            const int kn = kbn * 32;
            if (kn >= MEMM) {
                m_nxt0 = *(const int4*)(amq + kn - MEMM);
                m_nxt1 = *(const int4*)(amq + kn - MEMM + 4);
            }
        }
        uint32_t u[8] = {a_cur.x & 0xFFFFu, a_cur.x >> 16, a_cur.y & 0xFFFFu, a_cur.y >> 16,
                         a_cur.z & 0xFFFFu, a_cur.z >> 16, a_cur.w & 0xFFFFu, a_cur.w >> 16};
        int mm[8] = {mc0.x, mc0.y, mc0.z, mc0.w, mc1.x, mc1.y, mc1.z, mc1.w};
        const bool masked = (kb * 32 >= MEMM);
        float wv[8];
#pragma unroll
        for (int j = 0; j < 8; ++j) {
            float s = bf2f(u[j]);
            bool keep = (s >= thr);
            if (masked) keep = keep && (mm[j] != 0);
            wv[j] = keep ? __expf(s) : 0.f;
        }
        uint4 aq;
        asm("v_cvt_pk_bf16_f32 %0, %1, %2" : "=v"(aq.x) : "v"(wv[0]), "v"(wv[1]));
        asm("v_cvt_pk_bf16_f32 %0, %1, %2" : "=v"(aq.y) : "v"(wv[2]), "v"(wv[3]));
        asm("v_cvt_pk_bf16_f32 %0, %1, %2" : "=v"(aq.z) : "v"(wv[4]), "v"(wv[5]));
        asm("v_cvt_pk_bf16_f32 %0, %1, %2" : "=v"(aq.w) : "v"(wv[6]), "v"(wv[7]));
        bf16x8 af;
        *(uint4*)&af = aq;
#pragma unroll
        for (int nt = 0; nt < 4; ++nt) {
            bf16x8 bf;
            *(uint4*)&bf = b_cur[nt];
            acc[nt] = __builtin_amdgcn_mfma_f32_16x16x32_bf16(af, bf, acc[nt], 0, 0, 0);
        }
        acc5 = __builtin_amdgcn_mfma_f32_16x16x32_bf16(af, onesf, acc5, 0, 0, 0);
    }

    // ---- combine across K quarters (halving rounds) ----
    if (w >= 8) {
        float* dst = &red[w - 8][lane][0];
#pragma unroll
        for (int nt = 0; nt < 4; ++nt)
#pragma unroll
            for (int r = 0; r < 4; ++r) dst[nt * 4 + r] = acc[nt][r];
#pragma unroll
        for (int r = 0; r < 4; ++r) dst[16 + r] = acc5[r];
    }
    __syncthreads();
    if (w < 8) {
        const float* s = &red[w][lane][0];
#pragma unroll
        for (int nt = 0; nt < 4; ++nt)
#pragma unroll
            for (int r = 0; r < 4; ++r) acc[nt][r] += s[nt * 4 + r];
#pragma unroll
        for (int r = 0; r < 4; ++r) acc5[r] += s[16 + r];
    }
    __syncthreads();
    if (w >= 4 && w < 8) {
        float* dst = &red[w - 4][lane][0];
#pragma unroll
        for (int nt = 0; nt < 4; ++nt)
#pragma unroll
            for (int r = 0; r < 4; ++r) dst[nt * 4 + r] = acc[nt][r];
#pragma unroll
        for (int r = 0; r < 4; ++r) dst[16 + r] = acc5[r];
    }
    __syncthreads();
    if (w < 4) {
        const float* s = &red[w][lane][0];
#pragma unroll
        for (int nt = 0; nt < 4; ++nt)
#pragma unroll
            for (int r = 0; r < 4; ++r) acc[nt][r] += s[nt * 4 + r];
#pragma unroll
        for (int r = 0; r < 4; ++r) acc5[r] += s[16 + r];

        float rinv[4];
#pragma unroll
        for (int r = 0; r < 4; ++r) {
            float rs = __shfl(acc5[r], quad * 16, 64);
            rinv[r] = 1.0f / rs;
        }
#pragma unroll
        for (int nt = 0; nt < 4; ++nt) {
#pragma unroll
            for (int r = 0; r < 4; ++r) {
                int row = quad * 4 + r;
                float val = acc[nt][r] * rinv[r];
                attn_bf[((size_t)b * SS + m0 + row) * DD + h * HDD + nt * 16 + row16] = f2bf(val);
            }
        }
    }
}

extern "C" void kernel_launch(void* const* d_in, const int* in_sizes, int n_in,
                              void* d_out, int out_size, void* d_ws, size_t ws_size,
                              hipStream_t stream)
{
    const float* hidden = (const float*)d_in[0];
    const int*   amask  = (const int*)d_in[1];
    const float* past_k = (const float*)d_in[2];
    const float* past_v = (const float*)d_in[3];
    const float* Wq = (const float*)d_in[4];
    const float* bq = (const float*)d_in[5];
    const float* Wk = (const float*)d_in[6];
    const float* bk = (const float*)d_in[7];
    const float* Wv = (const float*)d_in[8];
    const float* bv = (const float*)d_in[9];
    const float* Wo = (const float*)d_in[10];
    const float* bo = (const float*)d_in[11];

    float* out    = (float*)d_out;
    float* nk_out = out + (size_t)BB * SS * DD;
    float* nv_out = nk_out + (size_t)BB * HH * MEMM * HDD;

    char* base = (char*)d_ws;
    size_t off = 0;
    auto alloc = [&](size_t bytes) {
        char* p = base + off;
        off += (bytes + 255) & ~(size_t)255;
        return p;
    };
    ushort_t* hb    = (ushort_t*)alloc((size_t)BB * SS * DD * 2);            // 8 MB
    ushort_t* WtAll = (ushort_t*)alloc((size_t)4 * DD * DD * 2);             // 8 MB
    ushort_t* q_bf  = (ushort_t*)alloc((size_t)BB * HH * SS * HDD * 2);      // 8 MB
    ushort_t* kbf   = (ushort_t*)alloc((size_t)BB * HH * KTOT * HDD * 2);    // 10 MB
    ushort_t* vbf   = (ushort_t*)alloc((size_t)BB * HH * KTOT * HDD * 2);    // 10 MB
    ushort_t* vt    = (ushort_t*)alloc((size_t)BB * HH * NKB * 4 * 512 * 2); // 10.5 MB packed
    ushort_t* abf   = (ushort_t*)alloc((size_t)BB * SS * DD * 2);            // 8 MB
    float* thr_arr  = (float*)alloc((size_t)NROWS * 4);
    size_t fixed = off;
    const size_t sbuf_full = (size_t)NROWS * KTOT * 2;                       // 335.5 MB packed
    int nchunks = 32;
    for (int c = 1; c <= 32; c <<= 1) {
        if (fixed + sbuf_full / c + 256 <= ws_size) { nchunks = c; break; }
    }
    ushort_t* sbuf = (ushort_t*)alloc(sbuf_full / nchunks);
    const int bhpc = (BB * HH) / nchunks;

    dim3 blk(256);

    cast_hidden_kernel<<<dim3(1024), blk, 0, stream>>>(hidden, hb);
    transw_kernel<<<dim3(16, 16, 4), blk, 0, stream>>>(Wq, Wk, Wv, Wo, WtAll);
    // fused QKV: one GEMM, N=3072 (Wq|Wk|Wv transposes adjacent in WtAll)
    gemm128_kernel<<<dim3(24, 32), blk, 0, stream>>>(
        hb, WtAll, 1, bq, bk, bv, nullptr, q_bf, kbf, vbf, nk_out, nv_out);
    cast_past_kernel<<<dim3(4096), blk, 0, stream>>>(past_k, past_v, kbf, vbf);
    transpose_v_kernel<<<dim3(KTOT / 64, BB * HH), blk, 0, stream>>>(vbf, vt);

    for (int ci = 0; ci < nchunks; ++ci) {
        int bh0 = ci * bhpc;
        score_kernel<<<dim3(KTOT / 256, SS / 64, bhpc), blk, 0, stream>>>(q_bf, kbf, sbuf, bh0);
        quant_kernel<<<dim3(bhpc * (SS / 16)), blk, 0, stream>>>(sbuf, thr_arr, bh0);
        pv_kernel<<<dim3(SS / 64, bhpc), dim3(1024), 0, stream>>>(sbuf, vt, thr_arr,
                                                                  amask, abf, bh0);
    }
    // O-projection
    gemm128_kernel<<<dim3(8, 32), blk, 0, stream>>>(
        abf, WtAll + (size_t)3 * DD * DD, 0, bo, nullptr, nullptr, out,
        nullptr, nullptr, nullptr, nullptr, nullptr);
}